// Round 9
// baseline (18.296 us; speedup 1.0000x reference)
//
#include <hip/hip_runtime.h>
#include <math.h>

#define BS 4
#define CH 256
#define XD 1024
#define N 128
#define NP 8128
#define TWO_PI_F 6.283185307179586f
#define PADU 132  // LDS row stride in u32 (half2 pairs): 528 B, 16B-aligned, 2-way bank alias only

typedef __fp16 h2v __attribute__((ext_vector_type(2)));

__device__ __forceinline__ h2v u2h(unsigned u) {
  union { unsigned u; h2v h; } x; x.u = u; return x.h;
}
__device__ __forceinline__ unsigned h2u(h2v h) {
  union { unsigned u; h2v h; } x; x.h = h; return x.u;
}

// ---------------------------------------------------------------------------
// Single fused kernel. grid (8,8,4) x 256 threads (R7's proven k1 shape).
//  phase 1: 16x16 pairdist tile (f16 LDS + v_dot2_f32_f16) + COMPLETE output
//           write out[e] = x[e] + (e in dims ? 0.5 : 1.0)*a[e]  (the 0.5 arm
//           IS the exact no-collision closed form x_new = x + 0.5*a).
//  phase 2: last-block-per-batch (device-scope counter, old&63==63) reduces
//           the 64 tile maxes; if the collision mask is empty (always, for
//           this data) it returns; otherwise it fixes up all 256 channels.
// No second kernel, no grid barrier, no counter reset (mod-64 trick works
// from any poisoned starting value; exactly one arrival per launch hits 63).
// ---------------------------------------------------------------------------
__global__ __launch_bounds__(256) void k_fused(
    const float* __restrict__ x, const float* __restrict__ a,
    const float* __restrict__ ru, const int* __restrict__ dims,
    float* __restrict__ vrS, float* __restrict__ mS,
    float* __restrict__ pmaxV, float* __restrict__ pmaxM,
    unsigned* __restrict__ cnt, float* __restrict__ out) {
  int ti = blockIdx.x, tj = blockIdx.y, b = blockIdx.z;
  int t = threadIdx.x;
  __shared__ unsigned sXi[16][PADU], sXj[16][PADU], sAi[16][PADU], sAj[16][PADU];
  __shared__ unsigned inset[XD / 32];
  __shared__ float wred[16];
  __shared__ int islast;
  __shared__ float mx2[2];
  __shared__ float xx[N], vv[N];

  if (t < XD / 32) inset[t] = 0u;
  __syncthreads();
  int d16 = t & 15, grp = t >> 4;
  if (t < N) atomicOr(&inset[dims[t] >> 5], 1u << (dims[t] & 31));
  int di = dims[ti * 16 + d16];
  int dj = dims[tj * 16 + d16];
  __syncthreads();

  // ---- full output write for this block's 4 rows (passthrough + fast path) ----
  {
    int B = (b << 6) + (tj << 3) + ti;  // 0..255
    int row = (B << 2) + (t >> 6);
    int q0 = t & 63;
    const float4* x4 = (const float4*)(x + (size_t)row * XD);
    const float4* a4 = (const float4*)(a + (size_t)row * XD);
    float4* o4 = (float4*)(out + (size_t)row * XD);
#pragma unroll
    for (int q = 0; q < 4; ++q) {
      int e = q0 + (q << 6);  // float4 index 0..255; elems 4e..4e+3
      unsigned nib = (inset[e >> 3] >> ((e & 7) * 4)) & 0xFu;
      float4 xv = x4[e], av = a4[e];
      float4 o;
      o.x = fmaf((nib & 1u) ? 0.5f : 1.0f, av.x, xv.x);
      o.y = fmaf((nib & 2u) ? 0.5f : 1.0f, av.y, xv.y);
      o.z = fmaf((nib & 4u) ? 0.5f : 1.0f, av.z, xv.z);
      o.w = fmaf((nib & 8u) ? 0.5f : 1.0f, av.w, xv.w);
      o4[e] = o;
    }
  }

  // ---- stage 4 slabs as packed f16 pairs: [16 dims][128 half2 ch-pairs] ----
  {
    const float* xb = x + (size_t)b * CH * XD;
    const float* ab = a + (size_t)b * CH * XD;
    int c0 = grp * 16;  // 16 consecutive channels per thread
#pragma unroll
    for (int s = 0; s < 4; ++s) {
      const float* src = (s & 1) ? ab : xb;
      int d = (s & 2) ? dj : di;
      unsigned pk[8];
#pragma unroll
      for (int k = 0; k < 8; ++k) {
        float f0 = src[(size_t)(c0 + 2 * k) * XD + d];
        float f1 = src[(size_t)(c0 + 2 * k + 1) * XD + d];
        pk[k] = h2u(__builtin_amdgcn_cvt_pkrtz(f0, f1));
      }
      unsigned* dst = (s & 2) ? ((s & 1) ? &sAj[d16][0] : &sXj[d16][0])
                              : ((s & 1) ? &sAi[d16][0] : &sXi[d16][0]);
      *(uint4*)&dst[grp * 8] = make_uint4(pk[0], pk[1], pk[2], pk[3]);
      *(uint4*)&dst[grp * 8 + 4] = make_uint4(pk[4], pk[5], pk[6], pk[7]);
    }
  }
  __syncthreads();

  // ---- inner loop: 8 channels per iteration via half2 sub + dot2 ----
  int ii = t >> 4, jj = t & 15;
  float accx = 0.f, accv = 0.f;
#pragma unroll 8
  for (int cq = 0; cq < 32; ++cq) {
    uint4 xi = *(const uint4*)&sXi[ii][cq * 4];
    uint4 xj = *(const uint4*)&sXj[jj][cq * 4];
    uint4 ai = *(const uint4*)&sAi[ii][cq * 4];
    uint4 aj = *(const uint4*)&sAj[jj][cq * 4];
    h2v d0 = u2h(xi.x) - u2h(xj.x);
    accx = __builtin_amdgcn_fdot2(d0, d0, accx, false);
    h2v d1 = u2h(xi.y) - u2h(xj.y);
    accx = __builtin_amdgcn_fdot2(d1, d1, accx, false);
    h2v d2 = u2h(xi.z) - u2h(xj.z);
    accx = __builtin_amdgcn_fdot2(d2, d2, accx, false);
    h2v d3 = u2h(xi.w) - u2h(xj.w);
    accx = __builtin_amdgcn_fdot2(d3, d3, accx, false);
    h2v e0 = u2h(ai.x) - u2h(aj.x);
    accv = __builtin_amdgcn_fdot2(e0, e0, accv, false);
    h2v e1 = u2h(ai.y) - u2h(aj.y);
    accv = __builtin_amdgcn_fdot2(e1, e1, accv, false);
    h2v e2 = u2h(ai.z) - u2h(aj.z);
    accv = __builtin_amdgcn_fdot2(e2, e2, accv, false);
    h2v e3 = u2h(ai.w) - u2h(aj.w);
    accv = __builtin_amdgcn_fdot2(e3, e3, accv, false);
  }
  float vr = sqrtf(accv);
  float mv = vr * expf(-sqrtf(accx));
  {
    int i = ti * 16 + ii, j = tj * 16 + jj;
    // agent-scope stores: visible cross-XCD to the (rare) slow-path reader
    __hip_atomic_store(&vrS[((size_t)b * N + i) * N + j], vr, __ATOMIC_RELAXED,
                       __HIP_MEMORY_SCOPE_AGENT);
    __hip_atomic_store(&mS[((size_t)b * N + i) * N + j], mv, __ATOMIC_RELAXED,
                       __HIP_MEMORY_SCOPE_AGENT);
  }

  // ---- per-tile max of vr and m ----
  float wv = vr, wm = mv;
#pragma unroll
  for (int off = 32; off; off >>= 1) {
    wv = fmaxf(wv, __shfl_xor(wv, off));
    wm = fmaxf(wm, __shfl_xor(wm, off));
  }
  int wid = t >> 6;
  if ((t & 63) == 0) { wred[wid] = wv; wred[8 + wid] = wm; }
  __syncthreads();
  if (t == 0) {
    int tile = (b << 6) + (ti << 3) + tj;
    __hip_atomic_store(&pmaxV[tile],
                       fmaxf(fmaxf(wred[0], wred[1]), fmaxf(wred[2], wred[3])),
                       __ATOMIC_RELAXED, __HIP_MEMORY_SCOPE_AGENT);
    __hip_atomic_store(&pmaxM[tile],
                       fmaxf(fmaxf(wred[8], wred[9]), fmaxf(wred[10], wred[11])),
                       __ATOMIC_RELAXED, __HIP_MEMORY_SCOPE_AGENT);
    __threadfence();  // release everything above before the counter bump
    unsigned old = __hip_atomic_fetch_add(&cnt[b], 1u, __ATOMIC_ACQ_REL,
                                          __HIP_MEMORY_SCOPE_AGENT);
    islast = ((old & 63u) == 63u);  // 64th arrival for batch b THIS launch
  }
  __syncthreads();
  if (!islast) return;

  // ---- last block of batch b: reduce tile maxes, decide, (rarely) fix up ----
  if (t < 64) {
    float pv = __hip_atomic_load(&pmaxV[(b << 6) + t], __ATOMIC_RELAXED,
                                 __HIP_MEMORY_SCOPE_AGENT);
    float pm = __hip_atomic_load(&pmaxM[(b << 6) + t], __ATOMIC_RELAXED,
                                 __HIP_MEMORY_SCOPE_AGENT);
#pragma unroll
    for (int off = 32; off; off >>= 1) {
      pv = fmaxf(pv, __shfl_xor(pv, off));
      pm = fmaxf(pm, __shfl_xor(pm, off));
    }
    if (t == 0) { mx2[0] = pv; mx2[1] = pm; }
  }
  __syncthreads();
  float vrmax = mx2[0], mmax = mx2[1];
  float inv = vrmax > 0.f ? 1.f / vrmax : 0.f;  // vrmax==0 -> all-false mask
  if (!(mmax * inv > 0.5f)) return;  // mask empty: fast path already exact

  // ---- slow path (general correctness; not taken for this input) ----
  for (int c = 0; c < CH; ++c) {
    int bc = (b << 8) + c;
    __syncthreads();
    if (t < N) {
      int d = dims[t];
      xx[t] = x[(size_t)bc * XD + d];
      vv[t] = a[(size_t)bc * XD + d];
    }
    __syncthreads();
    if (t < N) {
      int j = t;
      const float* mcol = mS + (size_t)b * N * N + j;
      const float* vcol = vrS + (size_t)b * N * N + j;
      const float* rub = ru + (size_t)bc * NP;
      float S = 0.f, sumV = 0.f, sumX = 0.f, R = 0.f;
      for (int i = 0; i < N; ++i) {
        float mvv = __hip_atomic_load(&mcol[(size_t)i * N], __ATOMIC_RELAXED,
                                      __HIP_MEMORY_SCOPE_AGENT);
        if (mvv * inv > 0.5f) {
          S += 1.f;
          sumV += vv[i];
          sumX += xx[i];
          float vrv = __hip_atomic_load(&vcol[(size_t)i * N], __ATOMIC_RELAXED,
                                        __HIP_MEMORY_SCOPE_AGENT);
          int p;
          float sgn;
          if (i < j) {
            p = i * N - ((i * (i + 1)) >> 1) + (j - i - 1);
            sgn = 1.f;
          } else {
            p = j * N - ((j * (j + 1)) >> 1) + (i - j - 1);
            sgn = -1.f;
          }
          R += sgn * TWO_PI_F * vrv * rub[p];
        }
      }
      float vj = vv[j];
      float v_new = vj + 0.5f * S * vj - 0.5f * sumV + R;
      float x_new = 0.5f * xx[j] + 0.5f * (xx[j] + sumX) / (S + 1.f) + 0.5f * v_new;
      out[(size_t)bc * XD + dims[j]] = x_new;
    }
  }
}

extern "C" void kernel_launch(void* const* d_in, const int* in_sizes, int n_in,
                              void* d_out, int out_size, void* d_ws, size_t ws_size,
                              hipStream_t stream) {
  const float* x = (const float*)d_in[0];
  // d_in[1] = v : unused by the reference computation
  const float* a = (const float*)d_in[2];
  const float* ru = (const float*)d_in[3];
  const int* dims = (const int*)d_in[4];
  float* out = (float*)d_out;

  float* vrS = (float*)d_ws;               // BS*N*N f32 (256 KB)
  float* mS = vrS + (size_t)BS * N * N;    // BS*N*N f32 (256 KB)
  float* pmaxV = mS + (size_t)BS * N * N;  // BS*64 f32
  float* pmaxM = pmaxV + BS * 64;          // BS*64 f32
  unsigned* cnt = (unsigned*)(pmaxM + BS * 64);  // BS u32 (never reset; mod-64)

  k_fused<<<dim3(8, 8, BS), 256, 0, stream>>>(x, a, ru, dims, vrS, mS, pmaxV,
                                              pmaxM, cnt, out);
}

// Round 10
// 16.738 us; speedup vs baseline: 1.0931x; 1.0931x over previous
//
#include <hip/hip_runtime.h>
#include <math.h>

#define BS 4
#define CH 256
#define XD 1024
#define N 128
#define NP 8128
#define TWO_PI_F 6.283185307179586f
#define PADU 132  // LDS row stride in u32 (half2 pairs): 528 B, 16B-aligned, 2-way bank alias only

typedef __fp16 h2v __attribute__((ext_vector_type(2)));

__device__ __forceinline__ h2v u2h(unsigned u) {
  union { unsigned u; h2v h; } x; x.u = u; return x.h;
}
__device__ __forceinline__ unsigned h2u(h2v h) {
  union { unsigned u; h2v h; } x; x.h = h; return x.u;
}

// Computes this thread's (ii,jj) pair of tile (TI_,TJ_): stages f16-packed
// slabs to LDS, then 256-channel dot2 reduction. Block-uniform control flow.
#define TILE_PAIR(TI_, TJ_, VROUT, MVOUT)                                      \
  {                                                                            \
    int di_ = dims[(TI_) * 16 + d16];                                          \
    int dj_ = dims[(TJ_) * 16 + d16];                                          \
    __syncthreads(); /* previous slab readers done */                          \
    int c0_ = grp * 16;                                                        \
    _Pragma("unroll") for (int s = 0; s < 4; ++s) {                            \
      const float* src = (s & 1) ? ab : xb;                                    \
      int d = (s & 2) ? dj_ : di_;                                             \
      unsigned pk[8];                                                          \
      _Pragma("unroll") for (int k = 0; k < 8; ++k) {                          \
        float f0 = src[(size_t)(c0_ + 2 * k) * XD + d];                        \
        float f1 = src[(size_t)(c0_ + 2 * k + 1) * XD + d];                    \
        pk[k] = h2u(__builtin_amdgcn_cvt_pkrtz(f0, f1));                       \
      }                                                                        \
      unsigned* dst = (s & 2) ? ((s & 1) ? &sAj[d16][0] : &sXj[d16][0])        \
                              : ((s & 1) ? &sAi[d16][0] : &sXi[d16][0]);       \
      *(uint4*)&dst[grp * 8] = make_uint4(pk[0], pk[1], pk[2], pk[3]);         \
      *(uint4*)&dst[grp * 8 + 4] = make_uint4(pk[4], pk[5], pk[6], pk[7]);     \
    }                                                                          \
    __syncthreads();                                                           \
    float accx_ = 0.f, accv_ = 0.f;                                            \
    _Pragma("unroll 8") for (int cq = 0; cq < 32; ++cq) {                      \
      uint4 xi = *(const uint4*)&sXi[ii][cq * 4];                              \
      uint4 xj = *(const uint4*)&sXj[jj][cq * 4];                              \
      uint4 ai = *(const uint4*)&sAi[ii][cq * 4];                              \
      uint4 aj = *(const uint4*)&sAj[jj][cq * 4];                              \
      h2v d0 = u2h(xi.x) - u2h(xj.x);                                          \
      accx_ = __builtin_amdgcn_fdot2(d0, d0, accx_, false);                    \
      h2v d1 = u2h(xi.y) - u2h(xj.y);                                          \
      accx_ = __builtin_amdgcn_fdot2(d1, d1, accx_, false);                    \
      h2v d2 = u2h(xi.z) - u2h(xj.z);                                          \
      accx_ = __builtin_amdgcn_fdot2(d2, d2, accx_, false);                    \
      h2v d3 = u2h(xi.w) - u2h(xj.w);                                          \
      accx_ = __builtin_amdgcn_fdot2(d3, d3, accx_, false);                    \
      h2v e0 = u2h(ai.x) - u2h(aj.x);                                          \
      accv_ = __builtin_amdgcn_fdot2(e0, e0, accv_, false);                    \
      h2v e1 = u2h(ai.y) - u2h(aj.y);                                          \
      accv_ = __builtin_amdgcn_fdot2(e1, e1, accv_, false);                    \
      h2v e2 = u2h(ai.z) - u2h(aj.z);                                          \
      accv_ = __builtin_amdgcn_fdot2(e2, e2, accv_, false);                    \
      h2v e3 = u2h(ai.w) - u2h(aj.w);                                          \
      accv_ = __builtin_amdgcn_fdot2(e3, e3, accv_, false);                    \
    }                                                                          \
    VROUT = sqrtf(accv_);                                                      \
    MVOUT = (VROUT)*expf(-sqrtf(accx_));                                       \
  }

// ---------------------------------------------------------------------------
// Single fused kernel, grid (8,8,4) x 256 threads (R7's proven shape).
//  fast path: 16x16 pairdist tile + COMPLETE output write
//             out[e] = x[e] + (e in dims ? 0.5 : 1.0)*a[e]  (0.5 arm == exact
//             no-collision closed form). Only per-tile maxes cross blocks
//             (agent-scope atomics, 3 ops/block).
//  last block per batch (mod-64 counter, reset-free): reduces 64 tile maxes;
//             if mask empty (always, this data) -> done. Else RECOMPUTES all
//             tiles itself (plain stores, block-local visibility) + fixes up
//             all 256 channels. No bulk cross-XCD traffic ever.
// ---------------------------------------------------------------------------
__global__ __launch_bounds__(256) void k_fused(
    const float* __restrict__ x, const float* __restrict__ a,
    const float* __restrict__ ru, const int* __restrict__ dims,
    float* __restrict__ vrS, float* __restrict__ mS,
    float* __restrict__ pmaxV, float* __restrict__ pmaxM,
    unsigned* __restrict__ cnt, float* __restrict__ out) {
  int ti = blockIdx.x, tj = blockIdx.y, b = blockIdx.z;
  int t = threadIdx.x;
  __shared__ unsigned sXi[16][PADU], sXj[16][PADU], sAi[16][PADU], sAj[16][PADU];
  __shared__ unsigned inset[XD / 32];
  __shared__ float wred[16];
  __shared__ int islast;
  __shared__ float mx2[2];
  __shared__ float xx[N], vv[N];

  int d16 = t & 15, grp = t >> 4;
  int ii = t >> 4, jj = t & 15;
  const float* xb = x + (size_t)b * CH * XD;
  const float* ab = a + (size_t)b * CH * XD;

  if (t < XD / 32) inset[t] = 0u;
  __syncthreads();
  if (t < N) atomicOr(&inset[dims[t] >> 5], 1u << (dims[t] & 31));
  __syncthreads();

  // ---- full output write for this block's 4 rows (passthrough + fast path) ----
  {
    int B = (b << 6) + (tj << 3) + ti;  // 0..255
    int row = (B << 2) + (t >> 6);
    int q0 = t & 63;
    const float4* x4 = (const float4*)(x + (size_t)row * XD);
    const float4* a4 = (const float4*)(a + (size_t)row * XD);
    float4* o4 = (float4*)(out + (size_t)row * XD);
#pragma unroll
    for (int q = 0; q < 4; ++q) {
      int e = q0 + (q << 6);  // float4 index 0..255
      unsigned nib = (inset[e >> 3] >> ((e & 7) * 4)) & 0xFu;
      float4 xv = x4[e], av = a4[e];
      float4 o;
      o.x = fmaf((nib & 1u) ? 0.5f : 1.0f, av.x, xv.x);
      o.y = fmaf((nib & 2u) ? 0.5f : 1.0f, av.y, xv.y);
      o.z = fmaf((nib & 4u) ? 0.5f : 1.0f, av.z, xv.z);
      o.w = fmaf((nib & 8u) ? 0.5f : 1.0f, av.w, xv.w);
      o4[e] = o;
    }
  }

  // ---- this block's tile ----
  float vr, mv;
  TILE_PAIR(ti, tj, vr, mv);

  // ---- per-tile max of vr and m ----
  float wv = vr, wm = mv;
#pragma unroll
  for (int off = 32; off; off >>= 1) {
    wv = fmaxf(wv, __shfl_xor(wv, off));
    wm = fmaxf(wm, __shfl_xor(wm, off));
  }
  int wid = t >> 6;
  if ((t & 63) == 0) { wred[wid] = wv; wred[8 + wid] = wm; }
  __syncthreads();
  if (t == 0) {
    int tile = (b << 6) + (ti << 3) + tj;
    __hip_atomic_store(&pmaxV[tile],
                       fmaxf(fmaxf(wred[0], wred[1]), fmaxf(wred[2], wred[3])),
                       __ATOMIC_RELAXED, __HIP_MEMORY_SCOPE_AGENT);
    __hip_atomic_store(&pmaxM[tile],
                       fmaxf(fmaxf(wred[8], wred[9]), fmaxf(wred[10], wred[11])),
                       __ATOMIC_RELAXED, __HIP_MEMORY_SCOPE_AGENT);
    // acq_rel RMW releases the two stores above; 64th arrival this launch
    // sees (old&63)==63 regardless of the counter's (poisoned) start value.
    unsigned old = __hip_atomic_fetch_add(&cnt[b], 1u, __ATOMIC_ACQ_REL,
                                          __HIP_MEMORY_SCOPE_AGENT);
    islast = ((old & 63u) == 63u);
  }
  __syncthreads();
  if (!islast) return;

  // ---- last block of batch b: reduce tile maxes, decide ----
  if (t < 64) {
    float pv = __hip_atomic_load(&pmaxV[(b << 6) + t], __ATOMIC_ACQUIRE,
                                 __HIP_MEMORY_SCOPE_AGENT);
    float pm = __hip_atomic_load(&pmaxM[(b << 6) + t], __ATOMIC_ACQUIRE,
                                 __HIP_MEMORY_SCOPE_AGENT);
#pragma unroll
    for (int off = 32; off; off >>= 1) {
      pv = fmaxf(pv, __shfl_xor(pv, off));
      pm = fmaxf(pm, __shfl_xor(pm, off));
    }
    if (t == 0) { mx2[0] = pv; mx2[1] = pm; }
  }
  __syncthreads();
  float vrmax = mx2[0], mmax = mx2[1];
  float inv = vrmax > 0.f ? 1.f / vrmax : 0.f;  // vrmax==0 -> all-false mask
  if (!(mmax * inv > 0.5f)) return;  // mask empty: fast path already exact

  // ---- slow path (general correctness; not taken for this input) ----
  // Recompute ALL tiles of batch b locally (plain stores; same block reads).
  for (int tt = 0; tt < 64; ++tt) {
    int ti2 = tt >> 3, tj2 = tt & 7;
    float vr2_, mv2_;
    TILE_PAIR(ti2, tj2, vr2_, mv2_);
    int i = ti2 * 16 + ii, j = tj2 * 16 + jj;
    vrS[((size_t)b * N + i) * N + j] = vr2_;
    mS[((size_t)b * N + i) * N + j] = mv2_;
  }
  __syncthreads();
  for (int c = 0; c < CH; ++c) {
    int bc = (b << 8) + c;
    __syncthreads();
    if (t < N) {
      int d = dims[t];
      xx[t] = x[(size_t)bc * XD + d];
      vv[t] = a[(size_t)bc * XD + d];
    }
    __syncthreads();
    if (t < N) {
      int j = t;
      const float* mcol = mS + (size_t)b * N * N + j;
      const float* vcol = vrS + (size_t)b * N * N + j;
      const float* rub = ru + (size_t)bc * NP;
      float S = 0.f, sumV = 0.f, sumX = 0.f, R = 0.f;
      for (int i = 0; i < N; ++i) {
        float mvv = mcol[(size_t)i * N];
        if (mvv * inv > 0.5f) {
          S += 1.f;
          sumV += vv[i];
          sumX += xx[i];
          float vrv = vcol[(size_t)i * N];
          int p;
          float sgn;
          if (i < j) {
            p = i * N - ((i * (i + 1)) >> 1) + (j - i - 1);
            sgn = 1.f;
          } else {
            p = j * N - ((j * (j + 1)) >> 1) + (i - j - 1);
            sgn = -1.f;
          }
          R += sgn * TWO_PI_F * vrv * rub[p];
        }
      }
      float vj = vv[j];
      float v_new = vj + 0.5f * S * vj - 0.5f * sumV + R;
      float x_new = 0.5f * xx[j] + 0.5f * (xx[j] + sumX) / (S + 1.f) + 0.5f * v_new;
      out[(size_t)bc * XD + dims[j]] = x_new;
    }
  }
}

extern "C" void kernel_launch(void* const* d_in, const int* in_sizes, int n_in,
                              void* d_out, int out_size, void* d_ws, size_t ws_size,
                              hipStream_t stream) {
  const float* x = (const float*)d_in[0];
  // d_in[1] = v : unused by the reference computation
  const float* a = (const float*)d_in[2];
  const float* ru = (const float*)d_in[3];
  const int* dims = (const int*)d_in[4];
  float* out = (float*)d_out;

  float* vrS = (float*)d_ws;               // BS*N*N f32 (slow path only)
  float* mS = vrS + (size_t)BS * N * N;    // BS*N*N f32 (slow path only)
  float* pmaxV = mS + (size_t)BS * N * N;  // BS*64 f32
  float* pmaxM = pmaxV + BS * 64;          // BS*64 f32
  unsigned* cnt = (unsigned*)(pmaxM + BS * 64);  // BS u32 (never reset; mod-64)

  k_fused<<<dim3(8, 8, BS), 256, 0, stream>>>(x, a, ru, dims, vrS, mS, pmaxV,
                                              pmaxM, cnt, out);
}

// Round 11
// 11.851 us; speedup vs baseline: 1.5439x; 1.4124x over previous
//
#include <hip/hip_runtime.h>
#include <math.h>

#define BS 4
#define CH 256
#define XD 1024
#define N 128
#define NP 8128
#define NTILE 36  // upper-triangle tiles of the 8x8 tile grid (ti<=tj)
#define NPASS 112 // passthrough blocks; 4*NTILE + NPASS = 256 = 1 block/CU
#define TWO_PI_F 6.283185307179586f
#define PADU 132  // LDS row stride in u32: 528 B, 16B-aligned, 2-way bank alias only

typedef __fp16 h2v __attribute__((ext_vector_type(2)));

__device__ __forceinline__ h2v u2h(unsigned u) {
  union { unsigned u; h2v h; } x; x.u = u; return x.h;
}
__device__ __forceinline__ unsigned h2u(h2v h) {
  union { unsigned u; h2v h; } x; x.h = h; return x.u;
}

// ---------------------------------------------------------------------------
// K1, grid 256 x 256 threads, two block roles (block-uniform branch):
//  blocks [0,144): one upper-triangle 16x16 pairdist tile each (f16 LDS +
//    v_dot2_f32_f16). vr/m are SYMMETRIC -> only ti<=tj tiles computed (36/64
//    of R7's tile work). Stores vrS/mS upper tiles + per-tile maxes.
//  blocks [144,256): the complete output write
//    out[e] = x[e] + (e in dims ? 0.5 : 1.0)*a[e]   (0.5 arm == exact
//    no-collision closed form x+0.5*a). Pure HBM role, runs concurrently
//    with the LDS-bound tile blocks on different CUs.
// ---------------------------------------------------------------------------
__global__ __launch_bounds__(256) void k1_pair_pass(
    const float* __restrict__ x, const float* __restrict__ a,
    const int* __restrict__ dims,
    float* __restrict__ vrS, float* __restrict__ mS,
    float* __restrict__ pmaxV, float* __restrict__ pmaxM,
    float* __restrict__ out) {
  int bid = blockIdx.x;
  int t = threadIdx.x;
  __shared__ unsigned sXi[16][PADU], sXj[16][PADU], sAi[16][PADU], sAj[16][PADU];
  __shared__ unsigned inset[XD / 32];
  __shared__ float wred[16];

  if (bid < BS * NTILE) {
    // ---------------- tile role ----------------
    int b = bid / NTILE, tt = bid % NTILE;
    int ti = 0;
    while (8 * (ti + 1) - ((ti + 1) * ti) / 2 <= tt) ++ti;  // uniform, <=8 iters
    int tj = ti + tt - (8 * ti - (ti * (ti - 1)) / 2);

    int d16 = t & 15, grp = t >> 4;
    int di = dims[ti * 16 + d16];
    int dj = dims[tj * 16 + d16];
    const float* xb = x + (size_t)b * CH * XD;
    const float* ab = a + (size_t)b * CH * XD;
    int c0 = grp * 16;  // 16 consecutive channels per thread
#pragma unroll
    for (int s = 0; s < 4; ++s) {
      const float* src = (s & 1) ? ab : xb;
      int d = (s & 2) ? dj : di;
      unsigned pk[8];
#pragma unroll
      for (int k = 0; k < 8; ++k) {
        float f0 = src[(size_t)(c0 + 2 * k) * XD + d];
        float f1 = src[(size_t)(c0 + 2 * k + 1) * XD + d];
        pk[k] = h2u(__builtin_amdgcn_cvt_pkrtz(f0, f1));
      }
      unsigned* dst = (s & 2) ? ((s & 1) ? &sAj[d16][0] : &sXj[d16][0])
                              : ((s & 1) ? &sAi[d16][0] : &sXi[d16][0]);
      *(uint4*)&dst[grp * 8] = make_uint4(pk[0], pk[1], pk[2], pk[3]);
      *(uint4*)&dst[grp * 8 + 4] = make_uint4(pk[4], pk[5], pk[6], pk[7]);
    }
    __syncthreads();

    int ii = t >> 4, jj = t & 15;
    float accx = 0.f, accv = 0.f;
#pragma unroll 8
    for (int cq = 0; cq < 32; ++cq) {
      uint4 xi = *(const uint4*)&sXi[ii][cq * 4];
      uint4 xj = *(const uint4*)&sXj[jj][cq * 4];
      uint4 ai = *(const uint4*)&sAi[ii][cq * 4];
      uint4 aj = *(const uint4*)&sAj[jj][cq * 4];
      h2v d0 = u2h(xi.x) - u2h(xj.x);
      accx = __builtin_amdgcn_fdot2(d0, d0, accx, false);
      h2v d1 = u2h(xi.y) - u2h(xj.y);
      accx = __builtin_amdgcn_fdot2(d1, d1, accx, false);
      h2v d2 = u2h(xi.z) - u2h(xj.z);
      accx = __builtin_amdgcn_fdot2(d2, d2, accx, false);
      h2v d3 = u2h(xi.w) - u2h(xj.w);
      accx = __builtin_amdgcn_fdot2(d3, d3, accx, false);
      h2v e0 = u2h(ai.x) - u2h(aj.x);
      accv = __builtin_amdgcn_fdot2(e0, e0, accv, false);
      h2v e1 = u2h(ai.y) - u2h(aj.y);
      accv = __builtin_amdgcn_fdot2(e1, e1, accv, false);
      h2v e2 = u2h(ai.z) - u2h(aj.z);
      accv = __builtin_amdgcn_fdot2(e2, e2, accv, false);
      h2v e3 = u2h(ai.w) - u2h(aj.w);
      accv = __builtin_amdgcn_fdot2(e3, e3, accv, false);
    }
    float vr = sqrtf(accv);
    float mv = vr * expf(-sqrtf(accx));
    int i = ti * 16 + ii, j = tj * 16 + jj;
    vrS[((size_t)b * N + i) * N + j] = vr;
    mS[((size_t)b * N + i) * N + j] = mv;

    float wv = vr, wm = mv;
#pragma unroll
    for (int off = 32; off; off >>= 1) {
      wv = fmaxf(wv, __shfl_xor(wv, off));
      wm = fmaxf(wm, __shfl_xor(wm, off));
    }
    int wid = t >> 6;
    if ((t & 63) == 0) { wred[wid] = wv; wred[8 + wid] = wm; }
    __syncthreads();
    if (t == 0) {
      pmaxV[b * NTILE + tt] = fmaxf(fmaxf(wred[0], wred[1]), fmaxf(wred[2], wred[3]));
      pmaxM[b * NTILE + tt] = fmaxf(fmaxf(wred[8], wred[9]), fmaxf(wred[10], wred[11]));
    }
  } else {
    // ---------------- passthrough role ----------------
    int pb = bid - BS * NTILE;  // 0..NPASS-1
    if (t < XD / 32) inset[t] = 0u;
    __syncthreads();
    if (t < N) atomicOr(&inset[dims[t] >> 5], 1u << (dims[t] & 31));
    __syncthreads();
    int r0 = (pb * (BS * CH)) / NPASS;
    int r1 = ((pb + 1) * (BS * CH)) / NPASS;
    for (int row = r0; row < r1; ++row) {
      const float4* x4 = (const float4*)(x + (size_t)row * XD);
      const float4* a4 = (const float4*)(a + (size_t)row * XD);
      float4* o4 = (float4*)(out + (size_t)row * XD);
      int e = t;  // float4 index 0..255
      unsigned nib = (inset[e >> 3] >> ((e & 7) * 4)) & 0xFu;
      float4 xv = x4[e], av = a4[e];
      float4 o;
      o.x = fmaf((nib & 1u) ? 0.5f : 1.0f, av.x, xv.x);
      o.y = fmaf((nib & 2u) ? 0.5f : 1.0f, av.y, xv.y);
      o.z = fmaf((nib & 4u) ? 0.5f : 1.0f, av.z, xv.z);
      o.w = fmaf((nib & 8u) ? 0.5f : 1.0f, av.w, xv.w);
      o4[e] = o;
    }
  }
}

// ---------------------------------------------------------------------------
// K2: conditional fixup. 32 blocks (8 c-groups x 4 batches) x 256 threads.
// Reduce the 36 per-tile maxes; if the collision mask is empty (always, for
// this data) exit immediately -- k1's passthrough already wrote the exact
// fast path. Otherwise recompute the masked update for 32 channels/block,
// reading the symmetric vrS/mS through a (min,max) index swap.
// ---------------------------------------------------------------------------
__global__ __launch_bounds__(256) void k2_fixup(
    const float* __restrict__ x, const float* __restrict__ a,
    const float* __restrict__ ru, const int* __restrict__ dims,
    const float* __restrict__ vrS, const float* __restrict__ mS,
    const float* __restrict__ pmaxV, const float* __restrict__ pmaxM,
    float* __restrict__ out) {
  int cg = blockIdx.x, b = blockIdx.y;
  int t = threadIdx.x;
  __shared__ float mx2[2];
  __shared__ float xx[N], vv[N];
  __shared__ int dsh[N];

  if (t < 64) {
    float pv = (t < NTILE) ? pmaxV[b * NTILE + t] : 0.f;
    float pm = (t < NTILE) ? pmaxM[b * NTILE + t] : 0.f;
#pragma unroll
    for (int off = 32; off; off >>= 1) {
      pv = fmaxf(pv, __shfl_xor(pv, off));
      pm = fmaxf(pm, __shfl_xor(pm, off));
    }
    if (t == 0) { mx2[0] = pv; mx2[1] = pm; }
  }
  __syncthreads();
  float vrmax = mx2[0], mmax = mx2[1];
  float inv = vrmax > 0.f ? 1.f / vrmax : 0.f;  // vrmax==0 -> all-false mask
  if (!(mmax * inv > 0.5f)) return;  // mask empty: fast path already exact

  // ---- slow path (general correctness; not taken for this input) ----
  if (t < N) dsh[t] = dims[t];
  for (int cc = 0; cc < 32; ++cc) {
    int c = (cg << 5) + cc;
    int bc = (b << 8) + c;
    __syncthreads();
    if (t < N) {
      int d = dsh[t];
      xx[t] = x[(size_t)bc * XD + d];
      vv[t] = a[(size_t)bc * XD + d];
    }
    __syncthreads();
    if (t < N) {
      int j = t;
      const float* rub = ru + (size_t)bc * NP;
      float S = 0.f, sumV = 0.f, sumX = 0.f, R = 0.f;
      for (int i = 0; i < N; ++i) {
        int lo = i < j ? i : j, hi = i < j ? j : i;  // symmetric upper storage
        size_t idx = ((size_t)b * N + lo) * N + hi;
        float mvv = mS[idx];
        if (mvv * inv > 0.5f) {
          S += 1.f;
          sumV += vv[i];
          sumX += xx[i];
          float vrv = vrS[idx];
          int p;
          float sgn;
          if (i < j) {
            p = i * N - ((i * (i + 1)) >> 1) + (j - i - 1);
            sgn = 1.f;
          } else {
            p = j * N - ((j * (j + 1)) >> 1) + (i - j - 1);
            sgn = -1.f;
          }
          R += sgn * TWO_PI_F * vrv * rub[p];
        }
      }
      float vj = vv[j];
      float v_new = vj + 0.5f * S * vj - 0.5f * sumV + R;
      float x_new = 0.5f * xx[j] + 0.5f * (xx[j] + sumX) / (S + 1.f) + 0.5f * v_new;
      out[(size_t)bc * XD + dsh[j]] = x_new;
    }
  }
}

extern "C" void kernel_launch(void* const* d_in, const int* in_sizes, int n_in,
                              void* d_out, int out_size, void* d_ws, size_t ws_size,
                              hipStream_t stream) {
  const float* x = (const float*)d_in[0];
  // d_in[1] = v : unused by the reference computation
  const float* a = (const float*)d_in[2];
  const float* ru = (const float*)d_in[3];
  const int* dims = (const int*)d_in[4];
  float* out = (float*)d_out;

  float* vrS = (float*)d_ws;               // BS*N*N f32 (upper tiles only)
  float* mS = vrS + (size_t)BS * N * N;    // BS*N*N f32 (upper tiles only)
  float* pmaxV = mS + (size_t)BS * N * N;  // BS*NTILE f32
  float* pmaxM = pmaxV + BS * NTILE;       // BS*NTILE f32

  k1_pair_pass<<<BS * NTILE + NPASS, 256, 0, stream>>>(x, a, dims, vrS, mS,
                                                       pmaxV, pmaxM, out);
  k2_fixup<<<dim3(8, BS), 256, 0, stream>>>(x, a, ru, dims, vrS, mS, pmaxV,
                                            pmaxM, out);
}